// Round 1
// baseline (368.536 us; speedup 1.0000x reference)
//
#include <hip/hip_runtime.h>
#include <hip/hip_bf16.h>
#include <math.h>

typedef __hip_bfloat16 bf16;

// dtype: inputs are f32 (measured round 3), but keep runtime detect via the
// first 32-bit word of a ones-vector: f32 -> 0x3F800000, bf16 -> 0x3F803F80.
__device__ __forceinline__ bool detect_bf16(const void* ones_vec) {
  return ((const unsigned int*)ones_vec)[0] == 0x3F803F80u;
}
__device__ __forceinline__ float ldf(const void* p, long idx, bool isb) {
  if (isb) return __bfloat162float(((const bf16*)p)[idx]);
  return ((const float*)p)[idx];
}
__device__ __forceinline__ void stf(void* p, long idx, float v, bool isb) {
  if (isb) ((bf16*)p)[idx] = __float2bfloat16(v);
  else     ((float*)p)[idx] = v;
}
// butterfly sum across the full 64-lane wave
__device__ __forceinline__ float wsum64(float x) {
#pragma unroll
  for (int off = 32; off > 0; off >>= 1) x += __shfl_xor(x, off, 64);
  return x;
}
// butterfly sum within each 32-lane half (valid when halves hold identical
// per-c data, or when only lanes 0..31 carry payload)
__device__ __forceinline__ float wsum32(float x) {
#pragma unroll
  for (int off = 16; off > 0; off >>= 1) x += __shfl_xor(x, off, 64);
  return x;
}

// ---------------------------------------------------------------------------
// Kernel 1 (fused): per-node pipeline + top-64 NN selection for residue i.
// (unchanged this round)
// grid 512, block 256.
// ---------------------------------------------------------------------------
__global__ __launch_bounds__(256) void k_node_topk(
    const void* __restrict__ xyz, const void* __restrict__ state,
    const void* __restrict__ msa, const void* __restrict__ seq1hot,
    const void* __restrict__ g_msa, const void* __restrict__ b_msa,
    const void* __restrict__ g_state, const void* __restrict__ b_state,
    const void* __restrict__ g_node, const void* __restrict__ b_node,
    const void* __restrict__ Wx, const void* __restrict__ bx,
    const void* __restrict__ Wvv,
    float* __restrict__ l0, float* __restrict__ CA, float* __restrict__ v,
    float* __restrict__ vproj, float* __restrict__ agg, float* __restrict__ v_agg,
    int* __restrict__ nbr)
{
  const bool isb = detect_bf16(g_msa);
  const int i = blockIdx.x;
  const int t = threadIdx.x;
  const int lane = t & 63, w = t >> 6;
  __shared__ float nin[312];
  __shared__ float wred[2][4];
  __shared__ float part[8][32];
  __shared__ float sxyz[9], sv9[9];
  __shared__ float cx[512], cy[512], cz[512];
  __shared__ unsigned long long key[512];

  // ---- stage all CAs from xyz (for topk; independent of node pipeline) ----
  for (int tt = t; tt < 512; tt += 256) {
    cx[tt] = ldf(xyz, tt * 9 + 3, isb);
    cy[tt] = ldf(xyz, tt * 9 + 4, isb);
    cz[tt] = ldf(xyz, tt * 9 + 5, isb);
  }

  // ---- msa LN (256): one element per thread ----
  float x = ldf(msa, i * 256 + t, isb);
  float s1 = wsum64(x), s2 = wsum64(x * x);
  if (lane == 0) { wred[0][w] = s1; wred[1][w] = s2; }
  if (t < 9) sxyz[t] = ldf(xyz, i * 9 + t, isb);
  __syncthreads();
  float S  = wred[0][0] + wred[0][1] + wred[0][2] + wred[0][3];
  float Sq = wred[1][0] + wred[1][1] + wred[1][2] + wred[1][3];
  float mu = S * (1.f / 256.f);
  float rs = rsqrtf(fmaxf(Sq * (1.f / 256.f) - mu * mu, 0.f) + 1e-5f);
  nin[t] = (x - mu) * rs * ldf(g_msa, t, isb) + ldf(b_msa, t, isb);
  if (t < 21) nin[256 + t] = ldf(seq1hot, i * 21 + t, isb);
  if (t < 3)  nin[309 + t] = 0.f;

  // ---- state LN (32): wave 0 only ----
  if (w == 0) {
    float sx  = (lane < 32) ? ldf(state, i * 32 + lane, isb) : 0.f;
    float Ss  = wsum64(sx), Ssq = wsum64(sx * sx);
    float mus = Ss * (1.f / 32.f);
    float rss = rsqrtf(fmaxf(Ssq * (1.f / 32.f) - mus * mus, 0.f) + 1e-5f);
    if (lane < 32)
      nin[277 + lane] = (sx - mus) * rss * ldf(g_state, lane, isb) + ldf(b_state, lane, isb);
  }
  __syncthreads();

  // ---- Wx GEMV: thread (c, g) handles rows f ≡ g (mod 8) ----
  const int c = t & 31, g = t >> 5;
  float acc = 0.f;
  for (int f = g; f < 309; f += 8) acc += nin[f] * ldf(Wx, f * 32 + c, isb);
  part[g][c] = acc;

  // ---- topk: distances + packed keys (cx ready since barrier 1) ----
  float xi = cx[i], yi = cy[i], zi = cz[i];
  for (int tt = t; tt < 512; tt += 256) {
    float dx = cx[tt] - xi, dy = cy[tt] - yi, dz = cz[tt] - zi;
    float d2 = dx * dx + dy * dy + dz * dz;
    unsigned int bits = (tt == i) ? 0x7f800000u : __float_as_uint(d2);  // diag -> +inf
    key[tt] = ((unsigned long long)bits << 32) | (unsigned int)tt;
  }
  __syncthreads();

  if (w == 0) {
    float a = 0.f;
    if (lane < 32) {
      a = ldf(bx, lane, isb);
#pragma unroll
      for (int gg = 0; gg < 8; ++gg) a += part[gg][lane];
    }
    float Sa = wsum32(a), Saq = wsum32(a * a);   // payload only in lanes 0..31
    float mn = Sa * (1.f / 32.f);
    float rn = rsqrtf(fmaxf(Saq * (1.f / 32.f) - mn * mn, 0.f) + 1e-5f);
    if (lane < 32)
      l0[i * 32 + lane] = (a - mn) * rn * ldf(g_node, lane, isb) + ldf(b_node, lane, isb);
  } else if (w == 1) {
    if (lane < 3) CA[i * 3 + lane] = sxyz[3 + lane];
    if (lane < 9) {
      float vv = sxyz[lane] - sxyz[3 + lane % 3];
      v[i * 9 + lane] = vv;
      sv9[lane] = vv;
    }
    if (lane < 32) agg[i * 32 + lane] = 0.f;
  } else if (w == 2) {
    if (lane < 9) v_agg[i * 9 + lane] = 0.f;
  }
  __syncthreads();
  if (w == 1 && lane < 9) {
    int o = lane / 3, xc = lane % 3;
    float s = 0.f;
#pragma unroll
    for (int ii = 0; ii < 3; ++ii) s += ldf(Wvv, ii * 3 + o, isb) * sv9[ii * 3 + xc];
    vproj[i * 9 + lane] = s;
  }

  // ---- bitonic sort of 512 keys; lowest 64 -> nbr ----
  for (int k = 2; k <= 512; k <<= 1) {
    for (int j = k >> 1; j > 0; j >>= 1) {
      __syncthreads();
      int tt  = threadIdx.x;
      int i0 = ((tt & ~(j - 1)) << 1) | (tt & (j - 1));
      int i1 = i0 | j;
      bool up = ((i0 & k) == 0);
      unsigned long long a = key[i0], b = key[i1];
      if ((a > b) == up) { key[i0] = b; key[i1] = a; }
    }
  }
  __syncthreads();
  if (threadIdx.x < 64)
    nbr[i * 64 + threadIdx.x] = (int)(key[threadIdx.x] & 0xffffffffu);
}

// ---------------------------------------------------------------------------
// Kernel 3 (v4): per-edge messages + scatter. 1024 blocks (i, half), 4
// waves, 8 edges/wave.
// Changes vs v3.1 (theory: latency/occupancy-bound, VGPR ~170 -> 3 blk/CU
// + 256-block tail):
//   * l0_i @ W1 hoisted to per-wave a1_base (loop-invariant): -32 MACs/step,
//     sinv shrinks 104->72 floats.
//   * W1 rows 32..103 staged in LDS transposed [32][76] (16B-aligned, 4-way
//     bank conflicts only): frees ~52 VGPRs.
//   * __launch_bounds__(256,4): cap at 128 VGPR -> 4 blocks/CU, no tail.
//   * coef reduction split across duplicated halves: 18 DS-ops vs 30.
//   * dual accumulators in e1/W1 GEMVs: halve dependent FMA chains.
// ---------------------------------------------------------------------------
__global__ __launch_bounds__(256, 4) void k_edge(
    const void* __restrict__ pair,
    const void* __restrict__ g_pair, const void* __restrict__ b_pair,
    const void* __restrict__ We1, const void* __restrict__ be1,
    const void* __restrict__ g_e1, const void* __restrict__ b_e1,
    const void* __restrict__ W1, const void* __restrict__ b1,
    const void* __restrict__ Wv,
    const int* __restrict__ nbr,
    const float* __restrict__ l0, const float* __restrict__ CA,
    const float* __restrict__ v, const float* __restrict__ vproj,
    float* __restrict__ agg, float* __restrict__ v_agg)
{
  const bool isb = detect_bf16(g_pair);
  __shared__ float ped[4][128];
  __shared__ float sinv[4][72];   // [l0_j 0..31 | we 32..63 | dn,sv 64..67 | 0 pad 68..71]
  __shared__ float sgeo[21];      // CAi[3], vi[9], vpi[9]
  __shared__ float W1L[32][76];   // W1[32+t][c] transposed; stride 76 (304B, 16B-aligned, 4-way)

  const int i    = blockIdx.x >> 1;
  const int half = blockIdx.x & 1;
  const int tid  = threadIdx.x;
  const int w = tid >> 6, lane = tid & 63;
  const int c = lane & 31, h = lane >> 5;

  if (tid < 3)  sgeo[tid] = CA[i * 3 + tid];
  else if (tid < 12) sgeo[tid] = v[i * 9 + (tid - 3)];
  else if (tid < 21) sgeo[tid] = vproj[i * 9 + (tid - 12)];

  // ---- stage W1 rows 32..103 transposed (f>=100 -> 0) ----
  for (int idx = tid; idx < 32 * 72; idx += 256) {
    int cc = idx & 31, t = idx >> 5;                  // coalesced over cc
    W1L[cc][t] = (32 + t < 100) ? ldf(W1, (32 + t) * 32 + cc, isb) : 0.f;
  }

  // ---- loop-invariant per-lane registers ----
  float we1r[64];
#pragma unroll
  for (int t = 0; t < 64; ++t) we1r[t] = ldf(We1, (h * 64 + t) * 32 + c, isb);
  const float gp0 = ldf(g_pair, 2 * lane, isb),     gp1 = ldf(g_pair, 2 * lane + 1, isb);
  const float bp0 = ldf(b_pair, 2 * lane, isb),     bp1 = ldf(b_pair, 2 * lane + 1, isb);
  const float be1c = ldf(be1, c, isb), ge1c = ldf(g_e1, c, isb);
  const float bee1c = ldf(b_e1, c, isb);
  float wvr[3];   // half h owns coef outputs o = 3h..3h+2
#pragma unroll
  for (int k = 0; k < 3; ++k) wvr[k] = ldf(Wv, c * 6 + 3 * h + k, isb);

  // ---- a1_base = b1[c] + sum_{f<32} l0_i[f] * W1[f][c]  (loop-invariant) ----
  float base = 0.f;
#pragma unroll
  for (int t = 0; t < 16; ++t) {
    int f = h * 16 + t;
    base += l0[i * 32 + f] * ldf(W1, f * 32 + c, isb);
  }
  base += __shfl_xor(base, 32, 64);
  base += ldf(b1, c, isb);

  if (h == 0 && c < 4) sinv[w][68 + c] = 0.f;   // wave-private pad
  __syncthreads();   // sgeo + W1L ready; the ONLY barrier

  const float cai0 = sgeo[0], cai1 = sgeo[1], cai2 = sgeo[2];

  // ---- software prefetch for step 0 ----
  int jn = nbr[i * 64 + half * 32 + w];
  float np0, np1;
  {
    const size_t pb = ((size_t)(i * 512 + jn)) * 128;
    if (isb) {
      np0 = __bfloat162float(((const bf16*)pair)[pb + 2 * lane]);
      np1 = __bfloat162float(((const bf16*)pair)[pb + 2 * lane + 1]);
    } else {
      float2 pp = ((const float2*)pair)[(pb >> 1) + lane];
      np0 = pp.x; np1 = pp.y;
    }
  }
  float nlj  = l0[jn * 32 + c];
  float ncax = CA[jn * 3 + 0], ncay = CA[jn * 3 + 1], ncaz = CA[jn * 3 + 2];

#pragma unroll 1
  for (int step = 0; step < 8; ++step) {
    const int j = jn;
    const float p0 = np0, p1 = np1, lj = nlj;
    const float cax = ncax, cay = ncay, caz = ncaz;

    // prefetch step+1
    if (step < 7) {
      jn = nbr[i * 64 + half * 32 + (step + 1) * 4 + w];
      const size_t pb = ((size_t)(i * 512 + jn)) * 128;
      if (isb) {
        np0 = __bfloat162float(((const bf16*)pair)[pb + 2 * lane]);
        np1 = __bfloat162float(((const bf16*)pair)[pb + 2 * lane + 1]);
      } else {
        float2 pp = ((const float2*)pair)[(pb >> 1) + lane];
        np0 = pp.x; np1 = pp.y;
      }
      nlj  = l0[jn * 32 + c];
      ncax = CA[jn * 3 + 0]; ncay = CA[jn * 3 + 1]; ncaz = CA[jn * 3 + 2];
    }

    // ---- pair-row LN (full-wave stats; ped distributed across 64 lanes) ----
    float S  = wsum64(p0 + p1);
    float Sq = wsum64(p0 * p0 + p1 * p1);
    float mu = S * (1.f / 128.f);
    float rs = rsqrtf(fmaxf(Sq * (1.f / 128.f) - mu * mu, 0.f) + 1e-5f);
    ped[w][2 * lane]     = (p0 - mu) * rs * gp0 + bp0;
    ped[w][2 * lane + 1] = (p1 - mu) * rs * gp1 + bp1;
    // wave-private LDS: compiler-inserted lgkmcnt orders write->read (r5-proven)

    // ---- e1 = LN(pe @ We1 + be1): broadcast float4 reads x register weights
    float acc0 = 0.f, acc1 = 0.f;
    {
      const float4* p4 = (const float4*)&ped[w][h * 64];
#pragma unroll
      for (int t = 0; t < 16; t += 2) {
        float4 pa = p4[t], pb = p4[t + 1];
        acc0 += pa.x * we1r[4 * t]     + pa.y * we1r[4 * t + 1]
              + pa.z * we1r[4 * t + 2] + pa.w * we1r[4 * t + 3];
        acc1 += pb.x * we1r[4 * t + 4] + pb.y * we1r[4 * t + 5]
              + pb.z * we1r[4 * t + 6] + pb.w * we1r[4 * t + 7];
      }
    }
    float acc = acc0 + acc1;
    acc += __shfl_xor(acc, 32, 64);   // halves now duplicated per c
    acc += be1c;
    float m2 = wsum32(acc) * (1.f / 32.f);
    float r2 = rsqrtf(fmaxf(wsum32(acc * acc) * (1.f / 32.f) - m2 * m2, 0.f) + 1e-5f);
    float we = (acc - m2) * r2 * ge1c + bee1c;

    // ---- geometry ----
    float dex = cax - cai0, dey = cay - cai1, dez = caz - cai2;
    float dn  = sqrtf(dex * dex + dey * dey + dez * dez);
    float idn = 1.f / (dn + 1e-8f);
    float dux = dex * idn, duy = dey * idn, duz = dez * idn;

    if (h == 0) { sinv[w][c] = lj; sinv[w][32 + c] = we; }
    if (lane == 0) {
      sinv[w][64] = dn;
      sinv[w][65] = sgeo[3] * dux + sgeo[4] * duy + sgeo[5] * duz;
      sinv[w][66] = sgeo[6] * dux + sgeo[7] * duy + sgeo[8] * duz;
      sinv[w][67] = sgeo[9] * dux + sgeo[10] * duy + sgeo[11] * duz;
    }

    // ---- m = gelu(a1_base + inv[32:] @ W1[32:] ) ----
    float b0a = 0.f, b1a = 0.f;
    {
      const float4* i4 = (const float4*)&sinv[w][h * 36];   // broadcast per half
      const float4* w4 = (const float4*)&W1L[c][h * 36];
#pragma unroll
      for (int t = 0; t < 8; t += 2) {
        float4 ia = i4[t],     wa = w4[t];
        float4 ib = i4[t + 1], wb = w4[t + 1];
        b0a += ia.x * wa.x + ia.y * wa.y + ia.z * wa.z + ia.w * wa.w;
        b1a += ib.x * wb.x + ib.y * wb.y + ib.z * wb.z + ib.w * wb.w;
      }
      float4 ia = i4[8], wa = w4[8];
      b0a += ia.x * wa.x + ia.y * wa.y + ia.z * wa.z + ia.w * wa.w;
    }
    float a1 = b0a + b1a;
    a1 += __shfl_xor(a1, 32, 64);
    a1 += base;
    float u  = 0.7978845608028654f * (a1 + 0.044715f * a1 * a1 * a1);
    float mm = 0.5f * a1 * (1.f + tanhf(u));   // jax.nn.gelu approximate=True

    if (h == 0) atomicAdd(&agg[j * 32 + c], mm);

    // coef = m @ Wv: half h reduces its 3 outputs (15 butterflies), then 3
    // shfls pull the other half's values to lanes 0..8.
    float co0 = wsum32(mm * wvr[0]);
    float co1 = wsum32(mm * wvr[1]);
    float co2 = wsum32(mm * wvr[2]);
    float ct0 = __shfl(co0, (lane & 31) + 32, 64);
    float ct1 = __shfl(co1, (lane & 31) + 32, 64);
    float ct2 = __shfl(co2, (lane & 31) + 32, 64);
    if (lane < 9) {
      int o = lane / 3, xx = lane % 3;
      float dcomp = (xx == 0) ? dex : ((xx == 1) ? dey : dez);
      float cd = (o == 0) ? co0 : ((o == 1) ? co1 : co2);        // o = 0..2 (h=0 lanes)
      float cv = (o == 0) ? ct0 : ((o == 1) ? ct1 : ct2);        // o = 3..5 from half 1
      atomicAdd(&v_agg[j * 9 + lane], cd * dcomp + cv * sgeo[12 + o * 3 + xx]);
    }
  }
}

// ---------------------------------------------------------------------------
// Kernel 4: output heads. grid 512, block 64. (unchanged)
// ---------------------------------------------------------------------------
__global__ __launch_bounds__(64) void k_out(
    const float* __restrict__ l0, const float* __restrict__ agg,
    const float* __restrict__ v, const float* __restrict__ v_agg,
    const float* __restrict__ CA,
    const void* __restrict__ W2, const void* __restrict__ b2,
    const void* __restrict__ Wself,
    const void* __restrict__ g_state, const void* __restrict__ b_state,
    const void* __restrict__ Wl, const void* __restrict__ bl,
    void* __restrict__ out)
{
  const bool isb = detect_bf16(g_state);
  const int l = blockIdx.x;
  const int lane = threadIdx.x;
  const int c = lane & 31, h = lane >> 5;
  __shared__ float scat[64], soff[9];
  if (lane < 32) { scat[lane] = l0[l * 32 + lane]; scat[32 + lane] = agg[l * 32 + lane]; }
  __syncthreads();

  // h_out = [l0, agg] @ W2 + b2 : lane (c,h), inner half each
  float acc = 0.f;
  {
    const int fb = h * 32;
    for (int f = 0; f < 32; ++f) acc += scat[fb + f] * ldf(W2, (fb + f) * 32 + c, isb);
  }
  acc += __shfl_xor(acc, 32, 64);
  acc += ldf(b2, c, isb);

  float mu = wsum32(acc) * (1.f / 32.f);
  float rs = rsqrtf(fmaxf(wsum32(acc * acc) * (1.f / 32.f) - mu * mu, 0.f) + 1e-5f);
  float hn = (acc - mu) * rs * ldf(g_state, c, isb) + ldf(b_state, c, isb);
  float pre = wsum32(hn * ldf(Wl, c, isb)) + ldf(bl, 0, isb);
  if (lane == 0) stf(out, 4608 + l, 1.f / (1.f + expf(-pre)), isb);

  if (lane < 9) {
    int o = lane / 3, xx = lane % 3;
    float s = v_agg[l * 9 + lane];
#pragma unroll
    for (int ii = 0; ii < 3; ++ii) s += ldf(Wself, ii * 3 + o, isb) * v[l * 9 + ii * 3 + xx];
    soff[lane] = s;
  }
  __syncthreads();
  if (lane < 9) {
    int xx = lane % 3;
    float add = (l == 0) ? 0.f : (CA[l * 3 + xx] + soff[3 + xx]);  // residue 0 zeroed
    stf(out, l * 9 + lane, soff[lane] + add, isb);
  }
}

extern "C" void kernel_launch(void* const* d_in, const int* in_sizes, int n_in,
                              void* d_out, int out_size, void* d_ws, size_t ws_size,
                              hipStream_t stream) {
  (void)in_sizes; (void)n_in; (void)out_size; (void)ws_size;
  const void* xyz     = d_in[0];
  const void* state   = d_in[1];
  const void* msa     = d_in[4];
  const void* pair    = d_in[5];
  const void* seq1hot = d_in[6];
  const void* g_msa   = d_in[10];
  const void* b_msa   = d_in[11];
  const void* g_pair  = d_in[12];
  const void* b_pair  = d_in[13];
  const void* g_state = d_in[14];
  const void* b_state = d_in[15];
  const void* g_node  = d_in[16];
  const void* b_node  = d_in[17];
  const void* g_e1    = d_in[18];
  const void* b_e1    = d_in[19];
  const void* Wx      = d_in[20];
  const void* bx      = d_in[21];
  const void* We1     = d_in[22];
  const void* be1     = d_in[23];
  const void* W1      = d_in[24];
  const void* b1      = d_in[25];
  const void* W2      = d_in[26];
  const void* b2      = d_in[27];
  const void* Wv      = d_in[28];
  const void* Wvv     = d_in[29];
  const void* Wself   = d_in[30];
  const void* Wl      = d_in[31];
  const void* bl      = d_in[32];

  float* ws    = (float*)d_ws;
  float* l0    = ws;            // 512*32
  float* CA    = ws + 16384;    // 512*3
  float* v     = ws + 17920;    // 512*9
  float* vproj = ws + 22528;    // 512*9
  float* agg   = ws + 27136;    // 512*32
  float* v_agg = ws + 43520;    // 512*9
  int*   nbr   = (int*)(ws + 48128);  // 512*64 ints

  hipLaunchKernelGGL(k_node_topk, dim3(512), dim3(256), 0, stream,
                     xyz, state, msa, seq1hot, g_msa, b_msa, g_state, b_state,
                     g_node, b_node, Wx, bx, Wvv, l0, CA, v, vproj, agg, v_agg, nbr);
  hipLaunchKernelGGL(k_edge, dim3(1024), dim3(256), 0, stream,
                     pair, g_pair, b_pair, We1, be1, g_e1, b_e1, W1, b1, Wv,
                     nbr, l0, CA, v, vproj, agg, v_agg);
  hipLaunchKernelGGL(k_out, dim3(512), dim3(64), 0, stream,
                     l0, agg, v, v_agg, CA, W2, b2, Wself, g_state, b_state, Wl, bl,
                     (void*)d_out);
}

// Round 2
// 315.978 us; speedup vs baseline: 1.1663x; 1.1663x over previous
//
#include <hip/hip_runtime.h>
#include <hip/hip_bf16.h>
#include <math.h>

typedef __hip_bfloat16 bf16;

// dtype: inputs are f32 (measured round 3), but keep runtime detect via the
// first 32-bit word of a ones-vector: f32 -> 0x3F800000, bf16 -> 0x3F803F80.
__device__ __forceinline__ bool detect_bf16(const void* ones_vec) {
  return ((const unsigned int*)ones_vec)[0] == 0x3F803F80u;
}
__device__ __forceinline__ float ldf(const void* p, long idx, bool isb) {
  if (isb) return __bfloat162float(((const bf16*)p)[idx]);
  return ((const float*)p)[idx];
}
__device__ __forceinline__ void stf(void* p, long idx, float v, bool isb) {
  if (isb) ((bf16*)p)[idx] = __float2bfloat16(v);
  else     ((float*)p)[idx] = v;
}
// butterfly sum across the full 64-lane wave
__device__ __forceinline__ float wsum64(float x) {
#pragma unroll
  for (int off = 32; off > 0; off >>= 1) x += __shfl_xor(x, off, 64);
  return x;
}
// butterfly sum within each 32-lane half (valid when halves hold identical
// per-c data, or when only lanes 0..31 carry payload)
__device__ __forceinline__ float wsum32(float x) {
#pragma unroll
  for (int off = 16; off > 0; off >>= 1) x += __shfl_xor(x, off, 64);
  return x;
}

// ---------------------------------------------------------------------------
// Kernel 1 (fused): per-node pipeline + top-64 NN selection for residue i.
// (unchanged this round)
// grid 512, block 256.
// ---------------------------------------------------------------------------
__global__ __launch_bounds__(256) void k_node_topk(
    const void* __restrict__ xyz, const void* __restrict__ state,
    const void* __restrict__ msa, const void* __restrict__ seq1hot,
    const void* __restrict__ g_msa, const void* __restrict__ b_msa,
    const void* __restrict__ g_state, const void* __restrict__ b_state,
    const void* __restrict__ g_node, const void* __restrict__ b_node,
    const void* __restrict__ Wx, const void* __restrict__ bx,
    const void* __restrict__ Wvv,
    float* __restrict__ l0, float* __restrict__ CA, float* __restrict__ v,
    float* __restrict__ vproj, float* __restrict__ agg, float* __restrict__ v_agg,
    int* __restrict__ nbr)
{
  const bool isb = detect_bf16(g_msa);
  const int i = blockIdx.x;
  const int t = threadIdx.x;
  const int lane = t & 63, w = t >> 6;
  __shared__ float nin[312];
  __shared__ float wred[2][4];
  __shared__ float part[8][32];
  __shared__ float sxyz[9], sv9[9];
  __shared__ float cx[512], cy[512], cz[512];
  __shared__ unsigned long long key[512];

  // ---- stage all CAs from xyz (for topk; independent of node pipeline) ----
  for (int tt = t; tt < 512; tt += 256) {
    cx[tt] = ldf(xyz, tt * 9 + 3, isb);
    cy[tt] = ldf(xyz, tt * 9 + 4, isb);
    cz[tt] = ldf(xyz, tt * 9 + 5, isb);
  }

  // ---- msa LN (256): one element per thread ----
  float x = ldf(msa, i * 256 + t, isb);
  float s1 = wsum64(x), s2 = wsum64(x * x);
  if (lane == 0) { wred[0][w] = s1; wred[1][w] = s2; }
  if (t < 9) sxyz[t] = ldf(xyz, i * 9 + t, isb);
  __syncthreads();
  float S  = wred[0][0] + wred[0][1] + wred[0][2] + wred[0][3];
  float Sq = wred[1][0] + wred[1][1] + wred[1][2] + wred[1][3];
  float mu = S * (1.f / 256.f);
  float rs = rsqrtf(fmaxf(Sq * (1.f / 256.f) - mu * mu, 0.f) + 1e-5f);
  nin[t] = (x - mu) * rs * ldf(g_msa, t, isb) + ldf(b_msa, t, isb);
  if (t < 21) nin[256 + t] = ldf(seq1hot, i * 21 + t, isb);
  if (t < 3)  nin[309 + t] = 0.f;

  // ---- state LN (32): wave 0 only ----
  if (w == 0) {
    float sx  = (lane < 32) ? ldf(state, i * 32 + lane, isb) : 0.f;
    float Ss  = wsum64(sx), Ssq = wsum64(sx * sx);
    float mus = Ss * (1.f / 32.f);
    float rss = rsqrtf(fmaxf(Ssq * (1.f / 32.f) - mus * mus, 0.f) + 1e-5f);
    if (lane < 32)
      nin[277 + lane] = (sx - mus) * rss * ldf(g_state, lane, isb) + ldf(b_state, lane, isb);
  }
  __syncthreads();

  // ---- Wx GEMV: thread (c, g) handles rows f ≡ g (mod 8) ----
  const int c = t & 31, g = t >> 5;
  float acc = 0.f;
  for (int f = g; f < 309; f += 8) acc += nin[f] * ldf(Wx, f * 32 + c, isb);
  part[g][c] = acc;

  // ---- topk: distances + packed keys (cx ready since barrier 1) ----
  float xi = cx[i], yi = cy[i], zi = cz[i];
  for (int tt = t; tt < 512; tt += 256) {
    float dx = cx[tt] - xi, dy = cy[tt] - yi, dz = cz[tt] - zi;
    float d2 = dx * dx + dy * dy + dz * dz;
    unsigned int bits = (tt == i) ? 0x7f800000u : __float_as_uint(d2);  // diag -> +inf
    key[tt] = ((unsigned long long)bits << 32) | (unsigned int)tt;
  }
  __syncthreads();

  if (w == 0) {
    float a = 0.f;
    if (lane < 32) {
      a = ldf(bx, lane, isb);
#pragma unroll
      for (int gg = 0; gg < 8; ++gg) a += part[gg][lane];
    }
    float Sa = wsum32(a), Saq = wsum32(a * a);   // payload only in lanes 0..31
    float mn = Sa * (1.f / 32.f);
    float rn = rsqrtf(fmaxf(Saq * (1.f / 32.f) - mn * mn, 0.f) + 1e-5f);
    if (lane < 32)
      l0[i * 32 + lane] = (a - mn) * rn * ldf(g_node, lane, isb) + ldf(b_node, lane, isb);
  } else if (w == 1) {
    if (lane < 3) CA[i * 3 + lane] = sxyz[3 + lane];
    if (lane < 9) {
      float vv = sxyz[lane] - sxyz[3 + lane % 3];
      v[i * 9 + lane] = vv;
      sv9[lane] = vv;
    }
    if (lane < 32) agg[i * 32 + lane] = 0.f;
  } else if (w == 2) {
    if (lane < 9) v_agg[i * 9 + lane] = 0.f;
  }
  __syncthreads();
  if (w == 1 && lane < 9) {
    int o = lane / 3, xc = lane % 3;
    float s = 0.f;
#pragma unroll
    for (int ii = 0; ii < 3; ++ii) s += ldf(Wvv, ii * 3 + o, isb) * sv9[ii * 3 + xc];
    vproj[i * 9 + lane] = s;
  }

  // ---- bitonic sort of 512 keys; lowest 64 -> nbr ----
  for (int k = 2; k <= 512; k <<= 1) {
    for (int j = k >> 1; j > 0; j >>= 1) {
      __syncthreads();
      int tt  = threadIdx.x;
      int i0 = ((tt & ~(j - 1)) << 1) | (tt & (j - 1));
      int i1 = i0 | j;
      bool up = ((i0 & k) == 0);
      unsigned long long a = key[i0], b = key[i1];
      if ((a > b) == up) { key[i0] = b; key[i1] = a; }
    }
  }
  __syncthreads();
  if (threadIdx.x < 64)
    nbr[i * 64 + threadIdx.x] = (int)(key[threadIdx.x] & 0xffffffffu);
}

// ---------------------------------------------------------------------------
// Kernel 3 (v5): per-edge messages + scatter. 1024 blocks (i, half), 4
// waves, 8 edges/wave.
// Post-mortem v4: __launch_bounds__(256,4) empirically capped VGPR at 64;
// we1r[64]+w1r register arrays spilled to scratch (FETCH 213MB, WRITE 58MB,
// 128us). v5 makes the register budget genuinely small instead of capping:
//   * BOTH weight arrays in block-shared LDS, transposed + padded for
//     float4 reads: We1T[32][132] (16.9KB), W1L[32][76] (9.7KB).
//   * a1_base hoist kept (l0_i @ W1 is loop-invariant): -32 MACs/step.
//   * __launch_bounds__(256,2): cap >=128; natural demand ~80-100, no spill.
//   * LDS ~30KB/block -> 4 blocks/CU -> all 1024 blocks co-resident.
// ---------------------------------------------------------------------------
__global__ __launch_bounds__(256, 2) void k_edge(
    const void* __restrict__ pair,
    const void* __restrict__ g_pair, const void* __restrict__ b_pair,
    const void* __restrict__ We1, const void* __restrict__ be1,
    const void* __restrict__ g_e1, const void* __restrict__ b_e1,
    const void* __restrict__ W1, const void* __restrict__ b1,
    const void* __restrict__ Wv,
    const int* __restrict__ nbr,
    const float* __restrict__ l0, const float* __restrict__ CA,
    const float* __restrict__ v, const float* __restrict__ vproj,
    float* __restrict__ agg, float* __restrict__ v_agg)
{
  const bool isb = detect_bf16(g_pair);
  __shared__ float ped[4][128];
  __shared__ float sinv[4][72];     // [l0_j 0..31 | we 32..63 | dn,sv 64..67 | 0 pad 68..71]
  __shared__ float sgeo[21];        // CAi[3], vi[9], vpi[9]
  __shared__ float We1T[32][132];   // We1[r][c] -> We1T[c][r]; stride 132 (528B, 16B-aligned)
  __shared__ float W1L[32][76];     // W1[32+t][c] -> W1L[c][t]; stride 76 (304B, 16B-aligned)

  const int i    = blockIdx.x >> 1;
  const int half = blockIdx.x & 1;
  const int tid  = threadIdx.x;
  const int w = tid >> 6, lane = tid & 63;
  const int c = lane & 31, h = lane >> 5;

  if (tid < 3)  sgeo[tid] = CA[i * 3 + tid];
  else if (tid < 12) sgeo[tid] = v[i * 9 + (tid - 3)];
  else if (tid < 21) sgeo[tid] = vproj[i * 9 + (tid - 12)];

  // ---- stage We1 transposed: We1T[cc][r] = We1[r*32+cc] (coalesced reads) ----
  for (int idx = tid; idx < 32 * 128; idx += 256) {
    int cc = idx & 31, r = idx >> 5;
    We1T[cc][r] = ldf(We1, r * 32 + cc, isb);
  }
  // ---- stage W1 rows 32..103 transposed (f>=100 -> 0) ----
  for (int idx = tid; idx < 32 * 72; idx += 256) {
    int cc = idx & 31, t = idx >> 5;
    W1L[cc][t] = (32 + t < 100) ? ldf(W1, (32 + t) * 32 + cc, isb) : 0.f;
  }

  // ---- loop-invariant per-lane registers (small) ----
  const float gp0 = ldf(g_pair, 2 * lane, isb),     gp1 = ldf(g_pair, 2 * lane + 1, isb);
  const float bp0 = ldf(b_pair, 2 * lane, isb),     bp1 = ldf(b_pair, 2 * lane + 1, isb);
  const float be1c = ldf(be1, c, isb), ge1c = ldf(g_e1, c, isb);
  const float bee1c = ldf(b_e1, c, isb);
  float wvr[3];   // half h owns coef outputs o = 3h..3h+2
#pragma unroll
  for (int k = 0; k < 3; ++k) wvr[k] = ldf(Wv, c * 6 + 3 * h + k, isb);

  // ---- a1_base = b1[c] + sum_{f<32} l0_i[f] * W1[f][c]  (loop-invariant) ----
  float base = 0.f;
#pragma unroll
  for (int t = 0; t < 16; ++t) {
    int f = h * 16 + t;
    base += l0[i * 32 + f] * ldf(W1, f * 32 + c, isb);
  }
  base += __shfl_xor(base, 32, 64);
  base += ldf(b1, c, isb);

  if (h == 0 && c < 4) sinv[w][68 + c] = 0.f;   // wave-private pad
  __syncthreads();   // sgeo + We1T + W1L ready; the ONLY barrier

  const float cai0 = sgeo[0], cai1 = sgeo[1], cai2 = sgeo[2];

  // ---- software prefetch for step 0 ----
  int jn = nbr[i * 64 + half * 32 + w];
  float np0, np1;
  {
    const size_t pb = ((size_t)(i * 512 + jn)) * 128;
    if (isb) {
      np0 = __bfloat162float(((const bf16*)pair)[pb + 2 * lane]);
      np1 = __bfloat162float(((const bf16*)pair)[pb + 2 * lane + 1]);
    } else {
      float2 pp = ((const float2*)pair)[(pb >> 1) + lane];
      np0 = pp.x; np1 = pp.y;
    }
  }
  float nlj  = l0[jn * 32 + c];
  float ncax = CA[jn * 3 + 0], ncay = CA[jn * 3 + 1], ncaz = CA[jn * 3 + 2];

#pragma unroll 1
  for (int step = 0; step < 8; ++step) {
    const int j = jn;
    const float p0 = np0, p1 = np1, lj = nlj;
    const float cax = ncax, cay = ncay, caz = ncaz;

    // prefetch step+1
    if (step < 7) {
      jn = nbr[i * 64 + half * 32 + (step + 1) * 4 + w];
      const size_t pb = ((size_t)(i * 512 + jn)) * 128;
      if (isb) {
        np0 = __bfloat162float(((const bf16*)pair)[pb + 2 * lane]);
        np1 = __bfloat162float(((const bf16*)pair)[pb + 2 * lane + 1]);
      } else {
        float2 pp = ((const float2*)pair)[(pb >> 1) + lane];
        np0 = pp.x; np1 = pp.y;
      }
      nlj  = l0[jn * 32 + c];
      ncax = CA[jn * 3 + 0]; ncay = CA[jn * 3 + 1]; ncaz = CA[jn * 3 + 2];
    }

    // ---- pair-row LN (full-wave stats; ped distributed across 64 lanes) ----
    float S  = wsum64(p0 + p1);
    float Sq = wsum64(p0 * p0 + p1 * p1);
    float mu = S * (1.f / 128.f);
    float rs = rsqrtf(fmaxf(Sq * (1.f / 128.f) - mu * mu, 0.f) + 1e-5f);
    ped[w][2 * lane]     = (p0 - mu) * rs * gp0 + bp0;
    ped[w][2 * lane + 1] = (p1 - mu) * rs * gp1 + bp1;
    // wave-private LDS: compiler-inserted lgkmcnt orders write->read (r5-proven)

    // ---- e1 = LN(pe @ We1 + be1): broadcast float4 x LDS weight float4 ----
    float acc0 = 0.f, acc1 = 0.f;
    {
      const float4* p4 = (const float4*)&ped[w][h * 64];
      const float4* w4 = (const float4*)&We1T[c][h * 64];
#pragma unroll
      for (int t = 0; t < 16; t += 2) {
        float4 pa = p4[t],     wa = w4[t];
        float4 pb = p4[t + 1], wb = w4[t + 1];
        acc0 += pa.x * wa.x + pa.y * wa.y + pa.z * wa.z + pa.w * wa.w;
        acc1 += pb.x * wb.x + pb.y * wb.y + pb.z * wb.z + pb.w * wb.w;
      }
    }
    float acc = acc0 + acc1;
    acc += __shfl_xor(acc, 32, 64);   // halves now duplicated per c
    acc += be1c;
    float m2 = wsum32(acc) * (1.f / 32.f);
    float r2 = rsqrtf(fmaxf(wsum32(acc * acc) * (1.f / 32.f) - m2 * m2, 0.f) + 1e-5f);
    float we = (acc - m2) * r2 * ge1c + bee1c;

    // ---- geometry ----
    float dex = cax - cai0, dey = cay - cai1, dez = caz - cai2;
    float dn  = sqrtf(dex * dex + dey * dey + dez * dez);
    float idn = 1.f / (dn + 1e-8f);
    float dux = dex * idn, duy = dey * idn, duz = dez * idn;

    if (h == 0) { sinv[w][c] = lj; sinv[w][32 + c] = we; }
    if (lane == 0) {
      sinv[w][64] = dn;
      sinv[w][65] = sgeo[3] * dux + sgeo[4] * duy + sgeo[5] * duz;
      sinv[w][66] = sgeo[6] * dux + sgeo[7] * duy + sgeo[8] * duz;
      sinv[w][67] = sgeo[9] * dux + sgeo[10] * duy + sgeo[11] * duz;
    }

    // ---- m = gelu(a1_base + inv[32:] @ W1[32:]) ----
    float b0a = 0.f, b1a = 0.f;
    {
      const float4* i4 = (const float4*)&sinv[w][h * 36];   // broadcast per half
      const float4* w4 = (const float4*)&W1L[c][h * 36];
#pragma unroll
      for (int t = 0; t < 8; t += 2) {
        float4 ia = i4[t],     wa = w4[t];
        float4 ib = i4[t + 1], wb = w4[t + 1];
        b0a += ia.x * wa.x + ia.y * wa.y + ia.z * wa.z + ia.w * wa.w;
        b1a += ib.x * wb.x + ib.y * wb.y + ib.z * wb.z + ib.w * wb.w;
      }
      float4 ia = i4[8], wa = w4[8];
      b0a += ia.x * wa.x + ia.y * wa.y + ia.z * wa.z + ia.w * wa.w;
    }
    float a1 = b0a + b1a;
    a1 += __shfl_xor(a1, 32, 64);
    a1 += base;
    float u  = 0.7978845608028654f * (a1 + 0.044715f * a1 * a1 * a1);
    float mm = 0.5f * a1 * (1.f + tanhf(u));   // jax.nn.gelu approximate=True

    if (h == 0) atomicAdd(&agg[j * 32 + c], mm);

    // coef = m @ Wv: half h reduces its 3 outputs (15 butterflies), then 3
    // shfls pull the other half's values to lanes 0..8.
    float co0 = wsum32(mm * wvr[0]);
    float co1 = wsum32(mm * wvr[1]);
    float co2 = wsum32(mm * wvr[2]);
    float ct0 = __shfl(co0, (lane & 31) + 32, 64);
    float ct1 = __shfl(co1, (lane & 31) + 32, 64);
    float ct2 = __shfl(co2, (lane & 31) + 32, 64);
    if (lane < 9) {
      int o = lane / 3, xx = lane % 3;
      float dcomp = (xx == 0) ? dex : ((xx == 1) ? dey : dez);
      float cd = (o == 0) ? co0 : ((o == 1) ? co1 : co2);        // o = 0..2 (h=0 lanes)
      float cv = (o == 0) ? ct0 : ((o == 1) ? ct1 : ct2);        // o = 3..5 from half 1
      atomicAdd(&v_agg[j * 9 + lane], cd * dcomp + cv * sgeo[12 + o * 3 + xx]);
    }
  }
}

// ---------------------------------------------------------------------------
// Kernel 4: output heads. grid 512, block 64. (unchanged)
// ---------------------------------------------------------------------------
__global__ __launch_bounds__(64) void k_out(
    const float* __restrict__ l0, const float* __restrict__ agg,
    const float* __restrict__ v, const float* __restrict__ v_agg,
    const float* __restrict__ CA,
    const void* __restrict__ W2, const void* __restrict__ b2,
    const void* __restrict__ Wself,
    const void* __restrict__ g_state, const void* __restrict__ b_state,
    const void* __restrict__ Wl, const void* __restrict__ bl,
    void* __restrict__ out)
{
  const bool isb = detect_bf16(g_state);
  const int l = blockIdx.x;
  const int lane = threadIdx.x;
  const int c = lane & 31, h = lane >> 5;
  __shared__ float scat[64], soff[9];
  if (lane < 32) { scat[lane] = l0[l * 32 + lane]; scat[32 + lane] = agg[l * 32 + lane]; }
  __syncthreads();

  // h_out = [l0, agg] @ W2 + b2 : lane (c,h), inner half each
  float acc = 0.f;
  {
    const int fb = h * 32;
    for (int f = 0; f < 32; ++f) acc += scat[fb + f] * ldf(W2, (fb + f) * 32 + c, isb);
  }
  acc += __shfl_xor(acc, 32, 64);
  acc += ldf(b2, c, isb);

  float mu = wsum32(acc) * (1.f / 32.f);
  float rs = rsqrtf(fmaxf(wsum32(acc * acc) * (1.f / 32.f) - mu * mu, 0.f) + 1e-5f);
  float hn = (acc - mu) * rs * ldf(g_state, c, isb) + ldf(b_state, c, isb);
  float pre = wsum32(hn * ldf(Wl, c, isb)) + ldf(bl, 0, isb);
  if (lane == 0) stf(out, 4608 + l, 1.f / (1.f + expf(-pre)), isb);

  if (lane < 9) {
    int o = lane / 3, xx = lane % 3;
    float s = v_agg[l * 9 + lane];
#pragma unroll
    for (int ii = 0; ii < 3; ++ii) s += ldf(Wself, ii * 3 + o, isb) * v[l * 9 + ii * 3 + xx];
    soff[lane] = s;
  }
  __syncthreads();
  if (lane < 9) {
    int xx = lane % 3;
    float add = (l == 0) ? 0.f : (CA[l * 3 + xx] + soff[3 + xx]);  // residue 0 zeroed
    stf(out, l * 9 + lane, soff[lane] + add, isb);
  }
}

extern "C" void kernel_launch(void* const* d_in, const int* in_sizes, int n_in,
                              void* d_out, int out_size, void* d_ws, size_t ws_size,
                              hipStream_t stream) {
  (void)in_sizes; (void)n_in; (void)out_size; (void)ws_size;
  const void* xyz     = d_in[0];
  const void* state   = d_in[1];
  const void* msa     = d_in[4];
  const void* pair    = d_in[5];
  const void* seq1hot = d_in[6];
  const void* g_msa   = d_in[10];
  const void* b_msa   = d_in[11];
  const void* g_pair  = d_in[12];
  const void* b_pair  = d_in[13];
  const void* g_state = d_in[14];
  const void* b_state = d_in[15];
  const void* g_node  = d_in[16];
  const void* b_node  = d_in[17];
  const void* g_e1    = d_in[18];
  const void* b_e1    = d_in[19];
  const void* Wx      = d_in[20];
  const void* bx      = d_in[21];
  const void* We1     = d_in[22];
  const void* be1     = d_in[23];
  const void* W1      = d_in[24];
  const void* b1      = d_in[25];
  const void* W2      = d_in[26];
  const void* b2      = d_in[27];
  const void* Wv      = d_in[28];
  const void* Wvv     = d_in[29];
  const void* Wself   = d_in[30];
  const void* Wl      = d_in[31];
  const void* bl      = d_in[32];

  float* ws    = (float*)d_ws;
  float* l0    = ws;            // 512*32
  float* CA    = ws + 16384;    // 512*3
  float* v     = ws + 17920;    // 512*9
  float* vproj = ws + 22528;    // 512*9
  float* agg   = ws + 27136;    // 512*32
  float* v_agg = ws + 43520;    // 512*9
  int*   nbr   = (int*)(ws + 48128);  // 512*64 ints

  hipLaunchKernelGGL(k_node_topk, dim3(512), dim3(256), 0, stream,
                     xyz, state, msa, seq1hot, g_msa, b_msa, g_state, b_state,
                     g_node, b_node, Wx, bx, Wvv, l0, CA, v, vproj, agg, v_agg, nbr);
  hipLaunchKernelGGL(k_edge, dim3(1024), dim3(256), 0, stream,
                     pair, g_pair, b_pair, We1, be1, g_e1, b_e1, W1, b1, Wv,
                     nbr, l0, CA, v, vproj, agg, v_agg);
  hipLaunchKernelGGL(k_out, dim3(512), dim3(64), 0, stream,
                     l0, agg, v, v_agg, CA, W2, b2, Wself, g_state, b_state, Wl, bl,
                     (void*)d_out);
}

// Round 3
// 306.861 us; speedup vs baseline: 1.2010x; 1.0297x over previous
//
#include <hip/hip_runtime.h>
#include <hip/hip_bf16.h>
#include <math.h>

typedef __hip_bfloat16 bf16;

// dtype: inputs are f32 (measured round 3), but keep runtime detect via the
// first 32-bit word of a ones-vector: f32 -> 0x3F800000, bf16 -> 0x3F803F80.
__device__ __forceinline__ bool detect_bf16(const void* ones_vec) {
  return ((const unsigned int*)ones_vec)[0] == 0x3F803F80u;
}
__device__ __forceinline__ float ldf(const void* p, long idx, bool isb) {
  if (isb) return __bfloat162float(((const bf16*)p)[idx]);
  return ((const float*)p)[idx];
}
__device__ __forceinline__ void stf(void* p, long idx, float v, bool isb) {
  if (isb) ((bf16*)p)[idx] = __float2bfloat16(v);
  else     ((float*)p)[idx] = v;
}
// butterfly sum across the full 64-lane wave
__device__ __forceinline__ float wsum64(float x) {
#pragma unroll
  for (int off = 32; off > 0; off >>= 1) x += __shfl_xor(x, off, 64);
  return x;
}
// butterfly sum within each 32-lane half (valid when halves hold identical
// per-c data, or when only lanes 0..31 carry payload)
__device__ __forceinline__ float wsum32(float x) {
#pragma unroll
  for (int off = 16; off > 0; off >>= 1) x += __shfl_xor(x, off, 64);
  return x;
}

// ---------------------------------------------------------------------------
// Kernel 1 (fused): per-node pipeline + top-64 NN selection for residue i.
// (unchanged this round)
// grid 512, block 256.
// ---------------------------------------------------------------------------
__global__ __launch_bounds__(256) void k_node_topk(
    const void* __restrict__ xyz, const void* __restrict__ state,
    const void* __restrict__ msa, const void* __restrict__ seq1hot,
    const void* __restrict__ g_msa, const void* __restrict__ b_msa,
    const void* __restrict__ g_state, const void* __restrict__ b_state,
    const void* __restrict__ g_node, const void* __restrict__ b_node,
    const void* __restrict__ Wx, const void* __restrict__ bx,
    const void* __restrict__ Wvv,
    float* __restrict__ l0, float* __restrict__ CA, float* __restrict__ v,
    float* __restrict__ vproj, float* __restrict__ agg, float* __restrict__ v_agg,
    int* __restrict__ nbr)
{
  const bool isb = detect_bf16(g_msa);
  const int i = blockIdx.x;
  const int t = threadIdx.x;
  const int lane = t & 63, w = t >> 6;
  __shared__ float nin[312];
  __shared__ float wred[2][4];
  __shared__ float part[8][32];
  __shared__ float sxyz[9], sv9[9];
  __shared__ float cx[512], cy[512], cz[512];
  __shared__ unsigned long long key[512];

  // ---- stage all CAs from xyz (for topk; independent of node pipeline) ----
  for (int tt = t; tt < 512; tt += 256) {
    cx[tt] = ldf(xyz, tt * 9 + 3, isb);
    cy[tt] = ldf(xyz, tt * 9 + 4, isb);
    cz[tt] = ldf(xyz, tt * 9 + 5, isb);
  }

  // ---- msa LN (256): one element per thread ----
  float x = ldf(msa, i * 256 + t, isb);
  float s1 = wsum64(x), s2 = wsum64(x * x);
  if (lane == 0) { wred[0][w] = s1; wred[1][w] = s2; }
  if (t < 9) sxyz[t] = ldf(xyz, i * 9 + t, isb);
  __syncthreads();
  float S  = wred[0][0] + wred[0][1] + wred[0][2] + wred[0][3];
  float Sq = wred[1][0] + wred[1][1] + wred[1][2] + wred[1][3];
  float mu = S * (1.f / 256.f);
  float rs = rsqrtf(fmaxf(Sq * (1.f / 256.f) - mu * mu, 0.f) + 1e-5f);
  nin[t] = (x - mu) * rs * ldf(g_msa, t, isb) + ldf(b_msa, t, isb);
  if (t < 21) nin[256 + t] = ldf(seq1hot, i * 21 + t, isb);
  if (t < 3)  nin[309 + t] = 0.f;

  // ---- state LN (32): wave 0 only ----
  if (w == 0) {
    float sx  = (lane < 32) ? ldf(state, i * 32 + lane, isb) : 0.f;
    float Ss  = wsum64(sx), Ssq = wsum64(sx * sx);
    float mus = Ss * (1.f / 32.f);
    float rss = rsqrtf(fmaxf(Ssq * (1.f / 32.f) - mus * mus, 0.f) + 1e-5f);
    if (lane < 32)
      nin[277 + lane] = (sx - mus) * rss * ldf(g_state, lane, isb) + ldf(b_state, lane, isb);
  }
  __syncthreads();

  // ---- Wx GEMV: thread (c, g) handles rows f ≡ g (mod 8) ----
  const int c = t & 31, g = t >> 5;
  float acc = 0.f;
  for (int f = g; f < 309; f += 8) acc += nin[f] * ldf(Wx, f * 32 + c, isb);
  part[g][c] = acc;

  // ---- topk: distances + packed keys (cx ready since barrier 1) ----
  float xi = cx[i], yi = cy[i], zi = cz[i];
  for (int tt = t; tt < 512; tt += 256) {
    float dx = cx[tt] - xi, dy = cy[tt] - yi, dz = cz[tt] - zi;
    float d2 = dx * dx + dy * dy + dz * dz;
    unsigned int bits = (tt == i) ? 0x7f800000u : __float_as_uint(d2);  // diag -> +inf
    key[tt] = ((unsigned long long)bits << 32) | (unsigned int)tt;
  }
  __syncthreads();

  if (w == 0) {
    float a = 0.f;
    if (lane < 32) {
      a = ldf(bx, lane, isb);
#pragma unroll
      for (int gg = 0; gg < 8; ++gg) a += part[gg][lane];
    }
    float Sa = wsum32(a), Saq = wsum32(a * a);   // payload only in lanes 0..31
    float mn = Sa * (1.f / 32.f);
    float rn = rsqrtf(fmaxf(Saq * (1.f / 32.f) - mn * mn, 0.f) + 1e-5f);
    if (lane < 32)
      l0[i * 32 + lane] = (a - mn) * rn * ldf(g_node, lane, isb) + ldf(b_node, lane, isb);
  } else if (w == 1) {
    if (lane < 3) CA[i * 3 + lane] = sxyz[3 + lane];
    if (lane < 9) {
      float vv = sxyz[lane] - sxyz[3 + lane % 3];
      v[i * 9 + lane] = vv;
      sv9[lane] = vv;
    }
    if (lane < 32) agg[i * 32 + lane] = 0.f;
  } else if (w == 2) {
    if (lane < 9) v_agg[i * 9 + lane] = 0.f;
  }
  __syncthreads();
  if (w == 1 && lane < 9) {
    int o = lane / 3, xc = lane % 3;
    float s = 0.f;
#pragma unroll
    for (int ii = 0; ii < 3; ++ii) s += ldf(Wvv, ii * 3 + o, isb) * sv9[ii * 3 + xc];
    vproj[i * 9 + lane] = s;
  }

  // ---- bitonic sort of 512 keys; lowest 64 -> nbr ----
  for (int k = 2; k <= 512; k <<= 1) {
    for (int j = k >> 1; j > 0; j >>= 1) {
      __syncthreads();
      int tt  = threadIdx.x;
      int i0 = ((tt & ~(j - 1)) << 1) | (tt & (j - 1));
      int i1 = i0 | j;
      bool up = ((i0 & k) == 0);
      unsigned long long a = key[i0], b = key[i1];
      if ((a > b) == up) { key[i0] = b; key[i1] = a; }
    }
  }
  __syncthreads();
  if (threadIdx.x < 64)
    nbr[i * 64 + threadIdx.x] = (int)(key[threadIdx.x] & 0xffffffffu);
}

// ---------------------------------------------------------------------------
// Kernel 3 (v6 = hybrid): per-edge messages + scatter. 1024 blocks (i, half),
// 4 waves, 8 edges/wave.
// Ledger: v3.1 (We1+W1 in regs, ~170 VGPR, no cap)        -> k_edge ~67us
//         v4   (regs + launch_bounds(256,4) -> 64-VGPR cap) -> spill, 128us
//         v5   (We1+W1 both in LDS, 4-way conflicts on e1)  -> 76us
// v6: We1 back in registers (hot GEMV, conflict-free broadcast x reg);
//     only the W1 tail stays in LDS (small GEMV, 9 float4/step);
//     a1_base hoist + split coef + dual accumulators kept;
//     NO 2nd launch_bounds arg (empirically arg=4 capped VGPR at 64).
//     Natural VGPR ~120-135 -> 3-4 waves/SIMD, no spill.
// ---------------------------------------------------------------------------
__global__ __launch_bounds__(256) void k_edge(
    const void* __restrict__ pair,
    const void* __restrict__ g_pair, const void* __restrict__ b_pair,
    const void* __restrict__ We1, const void* __restrict__ be1,
    const void* __restrict__ g_e1, const void* __restrict__ b_e1,
    const void* __restrict__ W1, const void* __restrict__ b1,
    const void* __restrict__ Wv,
    const int* __restrict__ nbr,
    const float* __restrict__ l0, const float* __restrict__ CA,
    const float* __restrict__ v, const float* __restrict__ vproj,
    float* __restrict__ agg, float* __restrict__ v_agg)
{
  const bool isb = detect_bf16(g_pair);
  __shared__ float ped[4][128];
  __shared__ float sinv[4][72];   // [l0_j 0..31 | we 32..63 | dn,sv 64..67 | 0 pad 68..71]
  __shared__ float sgeo[21];      // CAi[3], vi[9], vpi[9]
  __shared__ float W1L[32][76];   // W1[32+t][c] -> W1L[c][t]; stride 76 (304B, 16B-aligned)

  const int i    = blockIdx.x >> 1;
  const int half = blockIdx.x & 1;
  const int tid  = threadIdx.x;
  const int w = tid >> 6, lane = tid & 63;
  const int c = lane & 31, h = lane >> 5;

  if (tid < 3)  sgeo[tid] = CA[i * 3 + tid];
  else if (tid < 12) sgeo[tid] = v[i * 9 + (tid - 3)];
  else if (tid < 21) sgeo[tid] = vproj[i * 9 + (tid - 12)];

  // ---- stage W1 rows 32..103 transposed (f>=100 -> 0) ----
  for (int idx = tid; idx < 32 * 72; idx += 256) {
    int cc = idx & 31, t = idx >> 5;
    W1L[cc][t] = (32 + t < 100) ? ldf(W1, (32 + t) * 32 + cc, isb) : 0.f;
  }

  // ---- loop-invariant per-lane registers ----
  float we1r[64];
#pragma unroll
  for (int t = 0; t < 64; ++t) we1r[t] = ldf(We1, (h * 64 + t) * 32 + c, isb);
  const float gp0 = ldf(g_pair, 2 * lane, isb),     gp1 = ldf(g_pair, 2 * lane + 1, isb);
  const float bp0 = ldf(b_pair, 2 * lane, isb),     bp1 = ldf(b_pair, 2 * lane + 1, isb);
  const float be1c = ldf(be1, c, isb), ge1c = ldf(g_e1, c, isb);
  const float bee1c = ldf(b_e1, c, isb);
  float wvr[3];   // half h owns coef outputs o = 3h..3h+2
#pragma unroll
  for (int k = 0; k < 3; ++k) wvr[k] = ldf(Wv, c * 6 + 3 * h + k, isb);

  // ---- a1_base = b1[c] + sum_{f<32} l0_i[f] * W1[f][c]  (loop-invariant) ----
  float base = 0.f;
#pragma unroll
  for (int t = 0; t < 16; ++t) {
    int f = h * 16 + t;
    base += l0[i * 32 + f] * ldf(W1, f * 32 + c, isb);
  }
  base += __shfl_xor(base, 32, 64);
  base += ldf(b1, c, isb);

  if (h == 0 && c < 4) sinv[w][68 + c] = 0.f;   // wave-private pad
  __syncthreads();   // sgeo + W1L ready; the ONLY barrier

  const float cai0 = sgeo[0], cai1 = sgeo[1], cai2 = sgeo[2];

  // ---- software prefetch for step 0 ----
  int jn = nbr[i * 64 + half * 32 + w];
  float np0, np1;
  {
    const size_t pb = ((size_t)(i * 512 + jn)) * 128;
    if (isb) {
      np0 = __bfloat162float(((const bf16*)pair)[pb + 2 * lane]);
      np1 = __bfloat162float(((const bf16*)pair)[pb + 2 * lane + 1]);
    } else {
      float2 pp = ((const float2*)pair)[(pb >> 1) + lane];
      np0 = pp.x; np1 = pp.y;
    }
  }
  float nlj  = l0[jn * 32 + c];
  float ncax = CA[jn * 3 + 0], ncay = CA[jn * 3 + 1], ncaz = CA[jn * 3 + 2];

#pragma unroll 1
  for (int step = 0; step < 8; ++step) {
    const int j = jn;
    const float p0 = np0, p1 = np1, lj = nlj;
    const float cax = ncax, cay = ncay, caz = ncaz;

    // prefetch step+1
    if (step < 7) {
      jn = nbr[i * 64 + half * 32 + (step + 1) * 4 + w];
      const size_t pb = ((size_t)(i * 512 + jn)) * 128;
      if (isb) {
        np0 = __bfloat162float(((const bf16*)pair)[pb + 2 * lane]);
        np1 = __bfloat162float(((const bf16*)pair)[pb + 2 * lane + 1]);
      } else {
        float2 pp = ((const float2*)pair)[(pb >> 1) + lane];
        np0 = pp.x; np1 = pp.y;
      }
      nlj  = l0[jn * 32 + c];
      ncax = CA[jn * 3 + 0]; ncay = CA[jn * 3 + 1]; ncaz = CA[jn * 3 + 2];
    }

    // ---- pair-row LN (full-wave stats; ped distributed across 64 lanes) ----
    float S  = wsum64(p0 + p1);
    float Sq = wsum64(p0 * p0 + p1 * p1);
    float mu = S * (1.f / 128.f);
    float rs = rsqrtf(fmaxf(Sq * (1.f / 128.f) - mu * mu, 0.f) + 1e-5f);
    ped[w][2 * lane]     = (p0 - mu) * rs * gp0 + bp0;
    ped[w][2 * lane + 1] = (p1 - mu) * rs * gp1 + bp1;
    // wave-private LDS: compiler-inserted lgkmcnt orders write->read (r5-proven)

    // ---- e1 = LN(pe @ We1 + be1): broadcast float4 reads x register weights
    float acc0 = 0.f, acc1 = 0.f;
    {
      const float4* p4 = (const float4*)&ped[w][h * 64];
#pragma unroll
      for (int t = 0; t < 16; t += 2) {
        float4 pa = p4[t], pb = p4[t + 1];
        acc0 += pa.x * we1r[4 * t]     + pa.y * we1r[4 * t + 1]
              + pa.z * we1r[4 * t + 2] + pa.w * we1r[4 * t + 3];
        acc1 += pb.x * we1r[4 * t + 4] + pb.y * we1r[4 * t + 5]
              + pb.z * we1r[4 * t + 6] + pb.w * we1r[4 * t + 7];
      }
    }
    float acc = acc0 + acc1;
    acc += __shfl_xor(acc, 32, 64);   // halves now duplicated per c
    acc += be1c;
    float m2 = wsum32(acc) * (1.f / 32.f);
    float r2 = rsqrtf(fmaxf(wsum32(acc * acc) * (1.f / 32.f) - m2 * m2, 0.f) + 1e-5f);
    float we = (acc - m2) * r2 * ge1c + bee1c;

    // ---- geometry ----
    float dex = cax - cai0, dey = cay - cai1, dez = caz - cai2;
    float dn  = sqrtf(dex * dex + dey * dey + dez * dez);
    float idn = 1.f / (dn + 1e-8f);
    float dux = dex * idn, duy = dey * idn, duz = dez * idn;

    if (h == 0) { sinv[w][c] = lj; sinv[w][32 + c] = we; }
    if (lane == 0) {
      sinv[w][64] = dn;
      sinv[w][65] = sgeo[3] * dux + sgeo[4] * duy + sgeo[5] * duz;
      sinv[w][66] = sgeo[6] * dux + sgeo[7] * duy + sgeo[8] * duz;
      sinv[w][67] = sgeo[9] * dux + sgeo[10] * duy + sgeo[11] * duz;
    }

    // ---- m = gelu(a1_base + inv[32:] @ W1[32:]) ----
    float b0a = 0.f, b1a = 0.f;
    {
      const float4* i4 = (const float4*)&sinv[w][h * 36];   // broadcast per half
      const float4* w4 = (const float4*)&W1L[c][h * 36];
#pragma unroll
      for (int t = 0; t < 8; t += 2) {
        float4 ia = i4[t],     wa = w4[t];
        float4 ib = i4[t + 1], wb = w4[t + 1];
        b0a += ia.x * wa.x + ia.y * wa.y + ia.z * wa.z + ia.w * wa.w;
        b1a += ib.x * wb.x + ib.y * wb.y + ib.z * wb.z + ib.w * wb.w;
      }
      float4 ia = i4[8], wa = w4[8];
      b0a += ia.x * wa.x + ia.y * wa.y + ia.z * wa.z + ia.w * wa.w;
    }
    float a1 = b0a + b1a;
    a1 += __shfl_xor(a1, 32, 64);
    a1 += base;
    float u  = 0.7978845608028654f * (a1 + 0.044715f * a1 * a1 * a1);
    float mm = 0.5f * a1 * (1.f + tanhf(u));   // jax.nn.gelu approximate=True

    if (h == 0) atomicAdd(&agg[j * 32 + c], mm);

    // coef = m @ Wv: half h reduces its 3 outputs (15 butterflies), then 3
    // shfls pull the other half's values to lanes 0..8.
    float co0 = wsum32(mm * wvr[0]);
    float co1 = wsum32(mm * wvr[1]);
    float co2 = wsum32(mm * wvr[2]);
    float ct0 = __shfl(co0, (lane & 31) + 32, 64);
    float ct1 = __shfl(co1, (lane & 31) + 32, 64);
    float ct2 = __shfl(co2, (lane & 31) + 32, 64);
    if (lane < 9) {
      int o = lane / 3, xx = lane % 3;
      float dcomp = (xx == 0) ? dex : ((xx == 1) ? dey : dez);
      float cd = (o == 0) ? co0 : ((o == 1) ? co1 : co2);        // o = 0..2 (h=0 lanes)
      float cv = (o == 0) ? ct0 : ((o == 1) ? ct1 : ct2);        // o = 3..5 from half 1
      atomicAdd(&v_agg[j * 9 + lane], cd * dcomp + cv * sgeo[12 + o * 3 + xx]);
    }
  }
}

// ---------------------------------------------------------------------------
// Kernel 4: output heads. grid 512, block 64. (unchanged)
// ---------------------------------------------------------------------------
__global__ __launch_bounds__(64) void k_out(
    const float* __restrict__ l0, const float* __restrict__ agg,
    const float* __restrict__ v, const float* __restrict__ v_agg,
    const float* __restrict__ CA,
    const void* __restrict__ W2, const void* __restrict__ b2,
    const void* __restrict__ Wself,
    const void* __restrict__ g_state, const void* __restrict__ b_state,
    const void* __restrict__ Wl, const void* __restrict__ bl,
    void* __restrict__ out)
{
  const bool isb = detect_bf16(g_state);
  const int l = blockIdx.x;
  const int lane = threadIdx.x;
  const int c = lane & 31, h = lane >> 5;
  __shared__ float scat[64], soff[9];
  if (lane < 32) { scat[lane] = l0[l * 32 + lane]; scat[32 + lane] = agg[l * 32 + lane]; }
  __syncthreads();

  // h_out = [l0, agg] @ W2 + b2 : lane (c,h), inner half each
  float acc = 0.f;
  {
    const int fb = h * 32;
    for (int f = 0; f < 32; ++f) acc += scat[fb + f] * ldf(W2, (fb + f) * 32 + c, isb);
  }
  acc += __shfl_xor(acc, 32, 64);
  acc += ldf(b2, c, isb);

  float mu = wsum32(acc) * (1.f / 32.f);
  float rs = rsqrtf(fmaxf(wsum32(acc * acc) * (1.f / 32.f) - mu * mu, 0.f) + 1e-5f);
  float hn = (acc - mu) * rs * ldf(g_state, c, isb) + ldf(b_state, c, isb);
  float pre = wsum32(hn * ldf(Wl, c, isb)) + ldf(bl, 0, isb);
  if (lane == 0) stf(out, 4608 + l, 1.f / (1.f + expf(-pre)), isb);

  if (lane < 9) {
    int o = lane / 3, xx = lane % 3;
    float s = v_agg[l * 9 + lane];
#pragma unroll
    for (int ii = 0; ii < 3; ++ii) s += ldf(Wself, ii * 3 + o, isb) * v[l * 9 + ii * 3 + xx];
    soff[lane] = s;
  }
  __syncthreads();
  if (lane < 9) {
    int xx = lane % 3;
    float add = (l == 0) ? 0.f : (CA[l * 3 + xx] + soff[3 + xx]);  // residue 0 zeroed
    stf(out, l * 9 + lane, soff[lane] + add, isb);
  }
}

extern "C" void kernel_launch(void* const* d_in, const int* in_sizes, int n_in,
                              void* d_out, int out_size, void* d_ws, size_t ws_size,
                              hipStream_t stream) {
  (void)in_sizes; (void)n_in; (void)out_size; (void)ws_size;
  const void* xyz     = d_in[0];
  const void* state   = d_in[1];
  const void* msa     = d_in[4];
  const void* pair    = d_in[5];
  const void* seq1hot = d_in[6];
  const void* g_msa   = d_in[10];
  const void* b_msa   = d_in[11];
  const void* g_pair  = d_in[12];
  const void* b_pair  = d_in[13];
  const void* g_state = d_in[14];
  const void* b_state = d_in[15];
  const void* g_node  = d_in[16];
  const void* b_node  = d_in[17];
  const void* g_e1    = d_in[18];
  const void* b_e1    = d_in[19];
  const void* Wx      = d_in[20];
  const void* bx      = d_in[21];
  const void* We1     = d_in[22];
  const void* be1     = d_in[23];
  const void* W1      = d_in[24];
  const void* b1      = d_in[25];
  const void* W2      = d_in[26];
  const void* b2      = d_in[27];
  const void* Wv      = d_in[28];
  const void* Wvv     = d_in[29];
  const void* Wself   = d_in[30];
  const void* Wl      = d_in[31];
  const void* bl      = d_in[32];

  float* ws    = (float*)d_ws;
  float* l0    = ws;            // 512*32
  float* CA    = ws + 16384;    // 512*3
  float* v     = ws + 17920;    // 512*9
  float* vproj = ws + 22528;    // 512*9
  float* agg   = ws + 27136;    // 512*32
  float* v_agg = ws + 43520;    // 512*9
  int*   nbr   = (int*)(ws + 48128);  // 512*64 ints

  hipLaunchKernelGGL(k_node_topk, dim3(512), dim3(256), 0, stream,
                     xyz, state, msa, seq1hot, g_msa, b_msa, g_state, b_state,
                     g_node, b_node, Wx, bx, Wvv, l0, CA, v, vproj, agg, v_agg, nbr);
  hipLaunchKernelGGL(k_edge, dim3(1024), dim3(256), 0, stream,
                     pair, g_pair, b_pair, We1, be1, g_e1, b_e1, W1, b1, Wv,
                     nbr, l0, CA, v, vproj, agg, v_agg);
  hipLaunchKernelGGL(k_out, dim3(512), dim3(64), 0, stream,
                     l0, agg, v, v_agg, CA, W2, b2, Wself, g_state, b_state, Wl, bl,
                     (void*)d_out);
}

// Round 4
// 291.952 us; speedup vs baseline: 1.2623x; 1.0511x over previous
//
#include <hip/hip_runtime.h>
#include <hip/hip_bf16.h>
#include <math.h>

typedef __hip_bfloat16 bf16;

// dtype: inputs are f32 (measured round 3), but keep runtime detect via the
// first 32-bit word of a ones-vector: f32 -> 0x3F800000, bf16 -> 0x3F803F80.
__device__ __forceinline__ bool detect_bf16(const void* ones_vec) {
  return ((const unsigned int*)ones_vec)[0] == 0x3F803F80u;
}
__device__ __forceinline__ float ldf(const void* p, long idx, bool isb) {
  if (isb) return __bfloat162float(((const bf16*)p)[idx]);
  return ((const float*)p)[idx];
}
__device__ __forceinline__ void stf(void* p, long idx, float v, bool isb) {
  if (isb) ((bf16*)p)[idx] = __float2bfloat16(v);
  else     ((float*)p)[idx] = v;
}
// butterfly sum across the full 64-lane wave
__device__ __forceinline__ float wsum64(float x) {
#pragma unroll
  for (int off = 32; off > 0; off >>= 1) x += __shfl_xor(x, off, 64);
  return x;
}
// butterfly sum within each 32-lane half
__device__ __forceinline__ float wsum32(float x) {
#pragma unroll
  for (int off = 16; off > 0; off >>= 1) x += __shfl_xor(x, off, 64);
  return x;
}

// ---------------------------------------------------------------------------
// Kernel 1 (fused): per-node pipeline + top-64 NN selection for residue i.
// (unchanged this round)
// grid 512, block 256.
// ---------------------------------------------------------------------------
__global__ __launch_bounds__(256) void k_node_topk(
    const void* __restrict__ xyz, const void* __restrict__ state,
    const void* __restrict__ msa, const void* __restrict__ seq1hot,
    const void* __restrict__ g_msa, const void* __restrict__ b_msa,
    const void* __restrict__ g_state, const void* __restrict__ b_state,
    const void* __restrict__ g_node, const void* __restrict__ b_node,
    const void* __restrict__ Wx, const void* __restrict__ bx,
    const void* __restrict__ Wvv,
    float* __restrict__ l0, float* __restrict__ CA, float* __restrict__ v,
    float* __restrict__ vproj, float* __restrict__ agg, float* __restrict__ v_agg,
    int* __restrict__ nbr)
{
  const bool isb = detect_bf16(g_msa);
  const int i = blockIdx.x;
  const int t = threadIdx.x;
  const int lane = t & 63, w = t >> 6;
  __shared__ float nin[312];
  __shared__ float wred[2][4];
  __shared__ float part[8][32];
  __shared__ float sxyz[9], sv9[9];
  __shared__ float cx[512], cy[512], cz[512];
  __shared__ unsigned long long key[512];

  // ---- stage all CAs from xyz (for topk; independent of node pipeline) ----
  for (int tt = t; tt < 512; tt += 256) {
    cx[tt] = ldf(xyz, tt * 9 + 3, isb);
    cy[tt] = ldf(xyz, tt * 9 + 4, isb);
    cz[tt] = ldf(xyz, tt * 9 + 5, isb);
  }

  // ---- msa LN (256): one element per thread ----
  float x = ldf(msa, i * 256 + t, isb);
  float s1 = wsum64(x), s2 = wsum64(x * x);
  if (lane == 0) { wred[0][w] = s1; wred[1][w] = s2; }
  if (t < 9) sxyz[t] = ldf(xyz, i * 9 + t, isb);
  __syncthreads();
  float S  = wred[0][0] + wred[0][1] + wred[0][2] + wred[0][3];
  float Sq = wred[1][0] + wred[1][1] + wred[1][2] + wred[1][3];
  float mu = S * (1.f / 256.f);
  float rs = rsqrtf(fmaxf(Sq * (1.f / 256.f) - mu * mu, 0.f) + 1e-5f);
  nin[t] = (x - mu) * rs * ldf(g_msa, t, isb) + ldf(b_msa, t, isb);
  if (t < 21) nin[256 + t] = ldf(seq1hot, i * 21 + t, isb);
  if (t < 3)  nin[309 + t] = 0.f;

  // ---- state LN (32): wave 0 only ----
  if (w == 0) {
    float sx  = (lane < 32) ? ldf(state, i * 32 + lane, isb) : 0.f;
    float Ss  = wsum64(sx), Ssq = wsum64(sx * sx);
    float mus = Ss * (1.f / 32.f);
    float rss = rsqrtf(fmaxf(Ssq * (1.f / 32.f) - mus * mus, 0.f) + 1e-5f);
    if (lane < 32)
      nin[277 + lane] = (sx - mus) * rss * ldf(g_state, lane, isb) + ldf(b_state, lane, isb);
  }
  __syncthreads();

  // ---- Wx GEMV: thread (c, g) handles rows f ≡ g (mod 8) ----
  const int c = t & 31, g = t >> 5;
  float acc = 0.f;
  for (int f = g; f < 309; f += 8) acc += nin[f] * ldf(Wx, f * 32 + c, isb);
  part[g][c] = acc;

  // ---- topk: distances + packed keys (cx ready since barrier 1) ----
  float xi = cx[i], yi = cy[i], zi = cz[i];
  for (int tt = t; tt < 512; tt += 256) {
    float dx = cx[tt] - xi, dy = cy[tt] - yi, dz = cz[tt] - zi;
    float d2 = dx * dx + dy * dy + dz * dz;
    unsigned int bits = (tt == i) ? 0x7f800000u : __float_as_uint(d2);  // diag -> +inf
    key[tt] = ((unsigned long long)bits << 32) | (unsigned int)tt;
  }
  __syncthreads();

  if (w == 0) {
    float a = 0.f;
    if (lane < 32) {
      a = ldf(bx, lane, isb);
#pragma unroll
      for (int gg = 0; gg < 8; ++gg) a += part[gg][lane];
    }
    float Sa = wsum32(a), Saq = wsum32(a * a);   // payload only in lanes 0..31
    float mn = Sa * (1.f / 32.f);
    float rn = rsqrtf(fmaxf(Saq * (1.f / 32.f) - mn * mn, 0.f) + 1e-5f);
    if (lane < 32)
      l0[i * 32 + lane] = (a - mn) * rn * ldf(g_node, lane, isb) + ldf(b_node, lane, isb);
  } else if (w == 1) {
    if (lane < 3) CA[i * 3 + lane] = sxyz[3 + lane];
    if (lane < 9) {
      float vv = sxyz[lane] - sxyz[3 + lane % 3];
      v[i * 9 + lane] = vv;
      sv9[lane] = vv;
    }
    if (lane < 32) agg[i * 32 + lane] = 0.f;
  } else if (w == 2) {
    if (lane < 9) v_agg[i * 9 + lane] = 0.f;
  }
  __syncthreads();
  if (w == 1 && lane < 9) {
    int o = lane / 3, xc = lane % 3;
    float s = 0.f;
#pragma unroll
    for (int ii = 0; ii < 3; ++ii) s += ldf(Wvv, ii * 3 + o, isb) * sv9[ii * 3 + xc];
    vproj[i * 9 + lane] = s;
  }

  // ---- bitonic sort of 512 keys; lowest 64 -> nbr ----
  for (int k = 2; k <= 512; k <<= 1) {
    for (int j = k >> 1; j > 0; j >>= 1) {
      __syncthreads();
      int tt  = threadIdx.x;
      int i0 = ((tt & ~(j - 1)) << 1) | (tt & (j - 1));
      int i1 = i0 | j;
      bool up = ((i0 & k) == 0);
      unsigned long long a = key[i0], b = key[i1];
      if ((a > b) == up) { key[i0] = b; key[i1] = a; }
    }
  }
  __syncthreads();
  if (threadIdx.x < 64)
    nbr[i * 64 + threadIdx.x] = (int)(key[threadIdx.x] & 0xffffffffu);
}

// ---------------------------------------------------------------------------
// Kernel 3 (v7): BATCHED-PHASE edge kernel. grid 2048 = (i, quarter),
// block 256, 16 edges per block, processed in parallel phases instead of
// 8 serial per-wave steps.
// Ledger: v3.1/v6 (per-edge serial steps) -> 67us, ~20x above arithmetic
// roofline (latency-bound serial chains). v7 converts to throughput:
//   A: 16 threads/row load+LN pair rows (4-shfl stats)
//   B: e1 = LN(ped @ We1+be1) as 16x128x32 GEMM, thread = (col c, 2 rows);
//      weights in LDS WT[32][132], column-rotated (slot=(k4+4*(c&7))&31)
//      -> per-instr bank slot (5c+k4)%8 = permutation in c (conflict-free);
//      ped reads are half-wave broadcasts (free).
//   D: m = gelu(a1_base + inv[32:] @ W1tail) same mapping; WT re-staged
//      (buffer reuse) between barriers. a1_base hoist kept.
//   E: coef (96 threads) + v_agg scatter (144 threads).
// LDS ~34KB -> 4 blocks/CU -> grid 2048 = exactly 2 clean rounds.
// ---------------------------------------------------------------------------
__global__ __launch_bounds__(256) void k_edge(
    const void* __restrict__ pair,
    const void* __restrict__ g_pair, const void* __restrict__ b_pair,
    const void* __restrict__ We1, const void* __restrict__ be1,
    const void* __restrict__ g_e1, const void* __restrict__ b_e1,
    const void* __restrict__ W1, const void* __restrict__ b1,
    const void* __restrict__ Wv,
    const int* __restrict__ nbr,
    const float* __restrict__ l0, const float* __restrict__ CA,
    const float* __restrict__ v, const float* __restrict__ vproj,
    float* __restrict__ agg, float* __restrict__ v_agg)
{
  const bool isb = detect_bf16(g_pair);
  __shared__ float WT[32][132];    // phase B: We1^T (k 0..127); phase D: W1 tail (k 0..67); col-rotated
  __shared__ float ped[16][132];   // normalized pair rows
  __shared__ float sinvL[16][68];  // [l0_j 0..31 | e1n 32..63 | dn 64 | sv 65..67]
  __shared__ float mL[16][33];
  __shared__ float coefL[16][8];
  __shared__ float geoE[16][4];    // dex,dey,dez
  __shared__ float gpl[128], bpl[128];
  __shared__ float a1b[32];        // b1 + l0_i @ W1[0:32]
  __shared__ float sgeo[21];       // CA_i[3], v_i[9], vproj_i[9]
  __shared__ float wvL[6][33];     // wvL[o][c] = Wv[c*6+o]
  __shared__ int   jnL[16];

  const int i  = blockIdx.x >> 2;
  const int qt = blockIdx.x & 3;
  const int t  = threadIdx.x;
  const int e  = t >> 4;        // edge 0..15 (16 threads per edge)
  const int q  = t & 15;        // slice within row: elements [q*8, q*8+8)
  const int c  = t & 31;        // output column
  const int rg = t >> 5;        // row-group 0..7 -> rows 2rg, 2rg+1

  if (t < 16) jnL[t] = nbr[i * 64 + qt * 16 + t];
  __syncthreads();                                   // B1: jnL ready

  // ---- pair slice load (8 elems) — earliest (HBM) ----
  const int j_e = jnL[e];
  float4 pA, pB;
  {
    const size_t base = ((size_t)(i * 512 + j_e)) * 128 + q * 8;
    if (isb) {
      pA.x = ldf(pair, base + 0, true); pA.y = ldf(pair, base + 1, true);
      pA.z = ldf(pair, base + 2, true); pA.w = ldf(pair, base + 3, true);
      pB.x = ldf(pair, base + 4, true); pB.y = ldf(pair, base + 5, true);
      pB.z = ldf(pair, base + 6, true); pB.w = ldf(pair, base + 7, true);
    } else {
      const float4* p4 = (const float4*)pair;
      pA = p4[base >> 2]; pB = p4[(base >> 2) + 1];
    }
  }

  // ---- concurrent staging (overlaps pair-load latency) ----
  if (t < 128) gpl[t] = ldf(g_pair, t, isb);
  else         bpl[t - 128] = ldf(b_pair, t - 128, isb);
  // WT <- We1 transposed + column-rotated: element (c,k) at slot ((k>>2)+4*(c&7))&31
  for (int idx = t; idx < 4096; idx += 256) {
    int cc = idx & 31, k = idx >> 5;
    int slot = ((k >> 2) + 4 * (cc & 7)) & 31;
    WT[cc][slot * 4 + (k & 3)] = ldf(We1, idx, isb);
  }
  // l0_j -> sinvL[e][0..31] (2 elems/thread)
  {
    int ee = t >> 4, kk = (t & 15) * 2;
    const float2 lj = *(const float2*)&l0[jnL[ee] * 32 + kk];
    sinvL[ee][kk] = lj.x; sinvL[ee][kk + 1] = lj.y;
  }
  if (t < 3)       sgeo[t] = CA[i * 3 + t];
  else if (t < 12) sgeo[t] = v[i * 9 + (t - 3)];
  else if (t < 21) sgeo[t] = vproj[i * 9 + (t - 12)];
  if (t < 192) wvL[t % 6][t / 6] = ldf(Wv, t, isb);
  if (t < 32) {   // a1_base = b1[c] + l0_i @ W1[0:32,c]  (loop-invariant hoist)
    float b = ldf(b1, t, isb);
    for (int f = 0; f < 32; ++f) b += l0[i * 32 + f] * ldf(W1, f * 32 + t, isb);
    a1b[t] = b;
  }

  // ---- row LN stats: 16-lane butterfly over 8-elem partials ----
  float S  = pA.x + pA.y + pA.z + pA.w + pB.x + pB.y + pB.z + pB.w;
  float Sq = pA.x * pA.x + pA.y * pA.y + pA.z * pA.z + pA.w * pA.w
           + pB.x * pB.x + pB.y * pB.y + pB.z * pB.z + pB.w * pB.w;
#pragma unroll
  for (int off = 8; off > 0; off >>= 1) {
    S  += __shfl_xor(S,  off, 64);
    Sq += __shfl_xor(Sq, off, 64);
  }
  __syncthreads();                                   // B2: gpl/bpl, WT, sgeo, wvL, a1b, l0_j ready

  // ---- normalize slice -> ped ----
  {
    float mu = S * (1.f / 128.f);
    float rs = rsqrtf(fmaxf(Sq * (1.f / 128.f) - mu * mu, 0.f) + 1e-5f);
    float4 g0 = *(const float4*)&gpl[q * 8], g1 = *(const float4*)&gpl[q * 8 + 4];
    float4 b0 = *(const float4*)&bpl[q * 8], b1v = *(const float4*)&bpl[q * 8 + 4];
    float4 o0, o1;
    o0.x = (pA.x - mu) * rs * g0.x + b0.x;
    o0.y = (pA.y - mu) * rs * g0.y + b0.y;
    o0.z = (pA.z - mu) * rs * g0.z + b0.z;
    o0.w = (pA.w - mu) * rs * g0.w + b0.w;
    o1.x = (pB.x - mu) * rs * g1.x + b1v.x;
    o1.y = (pB.y - mu) * rs * g1.y + b1v.y;
    o1.z = (pB.z - mu) * rs * g1.z + b1v.z;
    o1.w = (pB.w - mu) * rs * g1.w + b1v.w;
    *(float4*)&ped[e][q * 8]     = o0;
    *(float4*)&ped[e][q * 8 + 4] = o1;
  }
  // ---- geometry per edge (sgeo safe after B2) ----
  if (t < 16) {
    int j = jnL[t];
    float dex = CA[j * 3 + 0] - sgeo[0];
    float dey = CA[j * 3 + 1] - sgeo[1];
    float dez = CA[j * 3 + 2] - sgeo[2];
    float dn  = sqrtf(dex * dex + dey * dey + dez * dez);
    float idn = 1.f / (dn + 1e-8f);
    float dux = dex * idn, duy = dey * idn, duz = dez * idn;
    sinvL[t][64] = dn;
    sinvL[t][65] = sgeo[3] * dux + sgeo[4] * duy + sgeo[5] * duz;
    sinvL[t][66] = sgeo[6] * dux + sgeo[7] * duy + sgeo[8] * duz;
    sinvL[t][67] = sgeo[9] * dux + sgeo[10] * duy + sgeo[11] * duz;
    geoE[t][0] = dex; geoE[t][1] = dey; geoE[t][2] = dez;
  }
  __syncthreads();                                   // B3: ped, geometry ready

  // ---- phase B: e1 GEMM [16x128]@[128x32], thread = (c, rows 2rg,2rg+1) ----
  const int e0 = rg * 2, e1i = rg * 2 + 1;
  const int rot = 4 * (c & 7);
  float A0 = ldf(be1, c, isb), A1 = A0;
#pragma unroll 4
  for (int k4 = 0; k4 < 32; ++k4) {
    float4 wf = *(const float4*)&WT[c][((k4 + rot) & 31) << 2];
    float4 p0 = *(const float4*)&ped[e0][k4 << 2];
    float4 p1 = *(const float4*)&ped[e1i][k4 << 2];
    A0 += p0.x * wf.x + p0.y * wf.y + p0.z * wf.z + p0.w * wf.w;
    A1 += p1.x * wf.x + p1.y * wf.y + p1.z * wf.z + p1.w * wf.w;
  }
  // e1 LN per row (stats across c within each 32-lane half)
  {
    const float ge1c = ldf(g_e1, c, isb), bee1c = ldf(b_e1, c, isb);
    float S0 = wsum32(A0), Q0 = wsum32(A0 * A0);
    float S1 = wsum32(A1), Q1 = wsum32(A1 * A1);
    float mu0 = S0 * (1.f / 32.f);
    float r0  = rsqrtf(fmaxf(Q0 * (1.f / 32.f) - mu0 * mu0, 0.f) + 1e-5f);
    float mu1 = S1 * (1.f / 32.f);
    float r1  = rsqrtf(fmaxf(Q1 * (1.f / 32.f) - mu1 * mu1, 0.f) + 1e-5f);
    sinvL[e0][32 + c]  = (A0 - mu0) * r0 * ge1c + bee1c;
    sinvL[e1i][32 + c] = (A1 - mu1) * r1 * ge1c + bee1c;
  }
  __syncthreads();                                   // B4: WT reads done, e1n written

  // ---- re-stage WT with W1 rows 32..99 (inv[32:100] weights) ----
  for (int idx = t; idx < 2176; idx += 256) {        // 68*32
    int cc = idx & 31, k = idx >> 5;
    int slot = ((k >> 2) + 4 * (cc & 7)) & 31;
    WT[cc][slot * 4 + (k & 3)] = ldf(W1, (32 + k) * 32 + cc, isb);
  }
  __syncthreads();                                   // B5

  // ---- phase D: m = gelu(a1b + inv[32:100] @ W1tail) ----
  {
    float M0 = a1b[c], M1 = M0;
#pragma unroll 4
    for (int k4 = 0; k4 < 17; ++k4) {
      float4 wf = *(const float4*)&WT[c][((k4 + rot) & 31) << 2];
      float4 s0 = *(const float4*)&sinvL[e0][k4 << 2];
      float4 s1 = *(const float4*)&sinvL[e1i][k4 << 2];
      M0 += s0.x * wf.x + s0.y * wf.y + s0.z * wf.z + s0.w * wf.w;
      M1 += s1.x * wf.x + s1.y * wf.y + s1.z * wf.z + s1.w * wf.w;
    }
    float u0 = 0.7978845608028654f * (M0 + 0.044715f * M0 * M0 * M0);
    float g0 = 0.5f * M0 * (1.f + tanhf(u0));
    float u1 = 0.7978845608028654f * (M1 + 0.044715f * M1 * M1 * M1);
    float g1 = 0.5f * M1 * (1.f + tanhf(u1));
    mL[e0][c] = g0;  mL[e1i][c] = g1;
    atomicAdd(&agg[jnL[e0] * 32 + c], g0);
    atomicAdd(&agg[jnL[e1i] * 32 + c], g1);
  }
  __syncthreads();                                   // B6: mL ready

  // ---- phase E: coef = m @ Wv ----
  if (t < 96) {
    int ee = t / 6, o = t - ee * 6;
    float s = 0.f;
#pragma unroll 8
    for (int cc = 0; cc < 32; ++cc) s += mL[ee][cc] * wvL[o][cc];
    coefL[ee][o] = s;
  }
  __syncthreads();                                   // B7: coef ready
  if (t < 144) {
    int ee = t / 9, l = t - ee * 9, o = l / 3, x = l - o * 3;
    float val = coefL[ee][o] * geoE[ee][x] + coefL[ee][3 + o] * sgeo[12 + o * 3 + x];
    atomicAdd(&v_agg[jnL[ee] * 9 + l], val);
  }
}

// ---------------------------------------------------------------------------
// Kernel 4: output heads. grid 512, block 64. (unchanged)
// ---------------------------------------------------------------------------
__global__ __launch_bounds__(64) void k_out(
    const float* __restrict__ l0, const float* __restrict__ agg,
    const float* __restrict__ v, const float* __restrict__ v_agg,
    const float* __restrict__ CA,
    const void* __restrict__ W2, const void* __restrict__ b2,
    const void* __restrict__ Wself,
    const void* __restrict__ g_state, const void* __restrict__ b_state,
    const void* __restrict__ Wl, const void* __restrict__ bl,
    void* __restrict__ out)
{
  const bool isb = detect_bf16(g_state);
  const int l = blockIdx.x;
  const int lane = threadIdx.x;
  const int c = lane & 31, h = lane >> 5;
  __shared__ float scat[64], soff[9];
  if (lane < 32) { scat[lane] = l0[l * 32 + lane]; scat[32 + lane] = agg[l * 32 + lane]; }
  __syncthreads();

  // h_out = [l0, agg] @ W2 + b2 : lane (c,h), inner half each
  float acc = 0.f;
  {
    const int fb = h * 32;
    for (int f = 0; f < 32; ++f) acc += scat[fb + f] * ldf(W2, (fb + f) * 32 + c, isb);
  }
  acc += __shfl_xor(acc, 32, 64);
  acc += ldf(b2, c, isb);

  float mu = wsum32(acc) * (1.f / 32.f);
  float rs = rsqrtf(fmaxf(wsum32(acc * acc) * (1.f / 32.f) - mu * mu, 0.f) + 1e-5f);
  float hn = (acc - mu) * rs * ldf(g_state, c, isb) + ldf(b_state, c, isb);
  float pre = wsum32(hn * ldf(Wl, c, isb)) + ldf(bl, 0, isb);
  if (lane == 0) stf(out, 4608 + l, 1.f / (1.f + expf(-pre)), isb);

  if (lane < 9) {
    int o = lane / 3, xx = lane % 3;
    float s = v_agg[l * 9 + lane];
#pragma unroll
    for (int ii = 0; ii < 3; ++ii) s += ldf(Wself, ii * 3 + o, isb) * v[l * 9 + ii * 3 + xx];
    soff[lane] = s;
  }
  __syncthreads();
  if (lane < 9) {
    int xx = lane % 3;
    float add = (l == 0) ? 0.f : (CA[l * 3 + xx] + soff[3 + xx]);  // residue 0 zeroed
    stf(out, l * 9 + lane, soff[lane] + add, isb);
  }
}

extern "C" void kernel_launch(void* const* d_in, const int* in_sizes, int n_in,
                              void* d_out, int out_size, void* d_ws, size_t ws_size,
                              hipStream_t stream) {
  (void)in_sizes; (void)n_in; (void)out_size; (void)ws_size;
  const void* xyz     = d_in[0];
  const void* state   = d_in[1];
  const void* msa     = d_in[4];
  const void* pair    = d_in[5];
  const void* seq1hot = d_in[6];
  const void* g_msa   = d_in[10];
  const void* b_msa   = d_in[11];
  const void* g_pair  = d_in[12];
  const void* b_pair  = d_in[13];
  const void* g_state = d_in[14];
  const void* b_state = d_in[15];
  const void* g_node  = d_in[16];
  const void* b_node  = d_in[17];
  const void* g_e1    = d_in[18];
  const void* b_e1    = d_in[19];
  const void* Wx      = d_in[20];
  const void* bx      = d_in[21];
  const void* We1     = d_in[22];
  const void* be1     = d_in[23];
  const void* W1      = d_in[24];
  const void* b1      = d_in[25];
  const void* W2      = d_in[26];
  const void* b2      = d_in[27];
  const void* Wv      = d_in[28];
  const void* Wvv     = d_in[29];
  const void* Wself   = d_in[30];
  const void* Wl      = d_in[31];
  const void* bl      = d_in[32];

  float* ws    = (float*)d_ws;
  float* l0    = ws;            // 512*32
  float* CA    = ws + 16384;    // 512*3
  float* v     = ws + 17920;    // 512*9
  float* vproj = ws + 22528;    // 512*9
  float* agg   = ws + 27136;    // 512*32
  float* v_agg = ws + 43520;    // 512*9
  int*   nbr   = (int*)(ws + 48128);  // 512*64 ints

  hipLaunchKernelGGL(k_node_topk, dim3(512), dim3(256), 0, stream,
                     xyz, state, msa, seq1hot, g_msa, b_msa, g_state, b_state,
                     g_node, b_node, Wx, bx, Wvv, l0, CA, v, vproj, agg, v_agg, nbr);
  hipLaunchKernelGGL(k_edge, dim3(2048), dim3(256), 0, stream,
                     pair, g_pair, b_pair, We1, be1, g_e1, b_e1, W1, b1, Wv,
                     nbr, l0, CA, v, vproj, agg, v_agg);
  hipLaunchKernelGGL(k_out, dim3(512), dim3(64), 0, stream,
                     l0, agg, v, v_agg, CA, W2, b2, Wself, g_state, b_state, Wl, bl,
                     (void*)d_out);
}